// Round 7
// baseline (2705.162 us; speedup 1.0000x reference)
//
#include <hip/hip_runtime.h>

#define NLVL 6
#define NN   32768
#define KFAN 8
#define FDIM 32
#define HDIM 256

typedef __attribute__((ext_vector_type(4))) float f32x4;
typedef __attribute__((ext_vector_type(8))) _Float16 f16x8;
typedef __attribute__((ext_vector_type(4))) unsigned short u16x4;

__device__ __forceinline__ float h2f(unsigned short u) {
    _Float16 h; __builtin_memcpy(&h, &u, 2); return (float)h;
}
__device__ __forceinline__ unsigned short f2h(float f) {
    _Float16 h = (_Float16)f;   // RNE
    unsigned short u; __builtin_memcpy(&u, &h, 2); return u;
}
__device__ __forceinline__ float tanh_fast(float x) {
    float e = __expf(2.0f * x);
    return 1.0f - 2.0f / (e + 1.0f);
}
__device__ __forceinline__ void gload16(const void* g, void* l) {
    __builtin_amdgcn_global_load_lds((const __attribute__((address_space(1))) void*)g,
                                     (__attribute__((address_space(3))) void*)l, 16, 0, 0);
}

// ---------------------------------------------------------------------------
// Paired fp16 B^T GEMM, 2-phase double-buffered (T3-minimal pipeline):
//   prologue: STAGE(buf0); barrier;
//   loop:     STAGE(buf^1, k+64); COMPUTE(buf); barrier; swap;
// The barrier's implicit vmcnt(0) drains the *next* tile's loads, which had
// the whole compute phase to land. One barrier per K-step.
// out = tanh(A[M,K] @ B[N,K]^T + bias) [+res if col<resW]; tile 128x128,
// 4 waves (2x2 of 64x64); M fixed = 32768 (256 row-blocks).
// Two GEMMs per launch via FLAT SCALAR args (no struct -> no scratch).
// LDS XOR-swizzled both-sides (pre-swizzled global src + swizzled ds_read).
// ---------------------------------------------------------------------------
__global__ __launch_bounds__(256)
void gemm_pair(const unsigned short* __restrict__ A0, const unsigned short* __restrict__ B0,
               const float* __restrict__ bias0, const unsigned short* __restrict__ res0,
               unsigned short* __restrict__ out0, float* __restrict__ outF0,
               int lda0, int ldb0, int ldr0, int ldo0, int resW0, int K0,
               const unsigned short* __restrict__ A1, const unsigned short* __restrict__ B1,
               const float* __restrict__ bias1, const unsigned short* __restrict__ res1,
               unsigned short* __restrict__ out1, float* __restrict__ outF1,
               int lda1, int ldb1, int ldr1, int ldo1, int resW1, int K1,
               int nblk0)
{
    const bool s = (int)blockIdx.x >= nblk0;
    const unsigned short* A    = s ? A1    : A0;
    const unsigned short* B    = s ? B1    : B0;
    const float*          bias = s ? bias1 : bias0;
    const unsigned short* res  = s ? res1  : res0;
    unsigned short*       outB = s ? out1  : out0;
    float*                outF = s ? outF1 : outF0;
    const int lda  = s ? lda1  : lda0;
    const int ldb  = s ? ldb1  : ldb0;
    const int ldr  = s ? ldr1  : ldr0;
    const int ldo  = s ? ldo1  : ldo0;
    const int resW = s ? resW1 : resW0;
    const int K    = s ? K1    : K0;
    const int bx   = (int)blockIdx.x - (s ? nblk0 : 0);
    const int brow = (bx & 255) * 128;
    const int bcol = (bx >> 8) * 128;

    __shared__ __align__(16) unsigned short sA[2][128 * 64];   // 32 KB
    __shared__ __align__(16) unsigned short sB[2][128 * 64];   // 32 KB

    const int tid  = threadIdx.x;
    const int wid  = tid >> 6;
    const int lane = tid & 63;
    const int wr   = wid >> 1, wc = wid & 1;        // wave quadrant (2x2)
    const int fr   = lane & 15, fq = lane >> 4;     // fragment row / k-group
    const int srow = lane >> 3;                     // staging row within chunk
    const int scol = ((lane & 7) ^ srow) * 8;       // pre-swizzled 16B col-block

    f32x4 acc[4][4] = {};

    auto STAGE = [&](int buf, int k0) {
        #pragma unroll
        for (int it = 0; it < 4; ++it) {
            const int c = wid * 4 + it;             // chunk 0..15 (wave-uniform)
            const int r = c * 8 + srow;             // tile row 0..127
            gload16(A + (size_t)(brow + r) * lda + k0 + scol, sA[buf] + c * 512);
            gload16(B + (size_t)(bcol + r) * ldb + k0 + scol, sB[buf] + c * 512);
        }
    };

    STAGE(0, 0);
    __syncthreads();
    int cur = 0;
    for (int k0 = 0; k0 < K; k0 += 64) {
        const bool more = (k0 + 64 < K);
        if (more) STAGE(cur ^ 1, k0 + 64);          // issue BEFORE compute
        #pragma unroll
        for (int ks = 0; ks < 2; ++ks) {            // two K=32 sub-steps
            f16x8 av[4], bv[4];
            #pragma unroll
            for (int m = 0; m < 4; ++m) {
                const int r = wr * 64 + m * 16 + fr;
                const int b = r * 128 + ((ks * 64 + fq * 16) ^ ((r & 7) << 4));
                av[m] = *(const f16x8*)((const char*)sA[cur] + b);
            }
            #pragma unroll
            for (int n = 0; n < 4; ++n) {
                const int r = wc * 64 + n * 16 + fr;
                const int b = r * 128 + ((ks * 64 + fq * 16) ^ ((r & 7) << 4));
                bv[n] = *(const f16x8*)((const char*)sB[cur] + b);
            }
            #pragma unroll
            for (int m = 0; m < 4; ++m)
                #pragma unroll
                for (int n = 0; n < 4; ++n)
                    acc[m][n] = __builtin_amdgcn_mfma_f32_16x16x32_f16(av[m], bv[n], acc[m][n], 0, 0, 0);
        }
        if (more) __syncthreads();                  // drains next-tile loads too
        cur ^= 1;
    }

    // epilogue: C/D layout col = lane&15, row = (lane>>4)*4 + j  [m89-verified]
    #pragma unroll
    for (int m = 0; m < 4; ++m) {
        #pragma unroll
        for (int n = 0; n < 4; ++n) {
            const int col = bcol + wc * 64 + n * 16 + fr;
            const float bb = bias[col];
            #pragma unroll
            for (int j = 0; j < 4; ++j) {
                const int row = brow + wr * 64 + m * 16 + fq * 4 + j;
                float v = acc[m][n][j] + bb;
                v = tanh_fast(v);
                if (res && col < resW) v += h2f(res[(size_t)row * ldr + col]);
                outB[(size_t)row * ldo + col] = f2h(v);
                if (outF) outF[(size_t)row * HDIM + col] = v;
            }
        }
    }
}

// ---------------------------------------------------------------------------
// Embed ALL levels: e_l = tanh(feats[l] @ We^T + be) -> ebuf[l] (fp16);
// level 0 also mirrored to out[0] (f32).
// ---------------------------------------------------------------------------
__global__ __launch_bounds__(256)
void embed_all(const float* __restrict__ feats,
               const float* __restrict__ We,
               const float* __restrict__ be,
               unsigned short* __restrict__ ebuf,
               float* __restrict__ out0)
{
    __shared__ float sW[256 * 33];   // +1 pad: kills bank conflicts on t*33+k
    __shared__ float sF[16 * 32];
    const int l   = blockIdx.x >> 11;       // / 2048 blocks per level
    const int blk = blockIdx.x & 2047;
    const int t = threadIdx.x;
    #pragma unroll
    for (int i = 0; i < 32; ++i) {
        int idx = t + 256 * i;
        sW[(idx >> 5) * 33 + (idx & 31)] = We[idx];
    }
    const size_t base = (size_t)blk * 16;
    const float* fl = feats + (size_t)l * NN * FDIM;
    for (int i = t; i < 16 * 32; i += 256) sF[i] = fl[base * 32 + i];
    __syncthreads();

    unsigned short* ob = ebuf + (size_t)l * NN * HDIM;
    const float bb = be[t];
    for (int r = 0; r < 16; ++r) {
        float a = bb;
        #pragma unroll
        for (int k = 0; k < 32; ++k) a += sF[r * 32 + k] * sW[t * 33 + k];
        const float v = tanh_fast(a);
        const size_t row = base + r;
        ob[row * HDIM + t] = f2h(v);
        if (l == 0) out0[row * HDIM + t] = v;
    }
}

// ---------------------------------------------------------------------------
// Gather-sum: msg[n,:] = sum_{k<8} e[idx[n,k],:]  (fp16 in, fp32 acc, fp16 out)
// ---------------------------------------------------------------------------
__global__ __launch_bounds__(256)
void gather_kernel(const unsigned short* __restrict__ ehalf,
                   const int* __restrict__ idx,
                   unsigned short* __restrict__ msg)
{
    const int n = blockIdx.x;
    const int t = threadIdx.x;
    const int* row = idx + (size_t)n * KFAN;
    float s = 0.f;
    #pragma unroll
    for (int k = 0; k < KFAN; ++k)
        s += h2f(ehalf[(size_t)row[k] * HDIM + t]);
    msg[(size_t)n * HDIM + t] = f2h(s);
}

// ---------------------------------------------------------------------------
// fp32 -> fp16 weight conversion
// ---------------------------------------------------------------------------
__global__ __launch_bounds__(256)
void cvt_kernel(const float* __restrict__ in, unsigned short* __restrict__ out, int n4)
{
    const int i = blockIdx.x * 256 + threadIdx.x;
    if (i >= n4) return;
    const float4 v = ((const float4*)in)[i];
    u16x4 o;
    o[0] = f2h(v.x); o[1] = f2h(v.y); o[2] = f2h(v.z); o[3] = f2h(v.w);
    ((u16x4*)out)[i] = o;
}

// ---------------------------------------------------------------------------
extern "C" void kernel_launch(void* const* d_in, const int* in_sizes, int n_in,
                              void* d_out, int out_size, void* d_ws, size_t ws_size,
                              hipStream_t stream)
{
    const float* feats    = (const float*)d_in[0];
    const int*   pred_idx = (const int*)d_in[1];
    const float* We       = (const float*)d_in[2];
    const float* be       = (const float*)d_in[3];
    const float* rs_b1    = (const float*)d_in[5];
    const float* rs_b2    = (const float*)d_in[7];
    const float* rs_b3    = (const float*)d_in[9];
    const float* rc_b1    = (const float*)d_in[11];
    const float* rc_b2    = (const float*)d_in[13];
    const float* rc_b3    = (const float*)d_in[15];
    float* out = (float*)d_out;

    // ---- workspace layout (fp16 everywhere) ----
    char* ws = (char*)d_ws;
    size_t off = 0;
    auto alloc = [&](size_t bytes) -> unsigned short* {
        unsigned short* p = (unsigned short*)(ws + off);
        off += (bytes + 255) & ~(size_t)255;
        return p;
    };
    unsigned short* rcW1b = alloc((size_t)6 * 512 * 512 * 2);
    unsigned short* rcW2b = alloc((size_t)6 * 512 * 512 * 2);
    unsigned short* rcW3b = alloc((size_t)6 * 256 * 512 * 2);
    unsigned short* rsW1b = alloc((size_t)12 * 256 * 256 * 2);
    unsigned short* rsW2b = alloc((size_t)12 * 256 * 256 * 2);
    unsigned short* rsW3b = alloc((size_t)12 * 256 * 256 * 2);
    unsigned short* ebuf  = alloc((size_t)NLVL * NN * 256 * 2);  // embeds of embed_op
    unsigned short* p0A   = alloc((size_t)NN * 512 * 2);   // [e', r] parity A
    unsigned short* p0B   = alloc((size_t)NN * 512 * 2);   // [e', r] parity B
    unsigned short* p1    = alloc((size_t)NN * 512 * 2);   // big h1 (comb & node share)
    unsigned short* p2    = alloc((size_t)NN * 512 * 2);   // big h2
    unsigned short* Tb    = alloc((size_t)NN * 256 * 2);   // big out (comb & node share)
    unsigned short* c1    = alloc((size_t)NN * 256 * 2);   // small h1
    unsigned short* c2    = alloc((size_t)NN * 256 * 2);   // small h2
    unsigned short* msgb  = alloc((size_t)NN * 256 * 2);
    unsigned short* t1    = alloc((size_t)NN * 256 * 2);
    unsigned short* t2    = alloc((size_t)NN * 256 * 2);
    unsigned short* t3    = alloc((size_t)NN * 256 * 2);
    unsigned short* ebfA  = alloc((size_t)NN * 256 * 2);
    unsigned short* ebfB  = alloc((size_t)NN * 256 * 2);
    (void)ws_size; (void)in_sizes; (void)n_in; (void)out_size;

    // ---- convert weights fp32 -> fp16 ----
    auto cvt = [&](const float* src, unsigned short* dst, int n) {
        int n4 = n / 4;
        cvt_kernel<<<dim3((n4 + 255) / 256), dim3(256), 0, stream>>>(src, dst, n4);
    };
    cvt((const float*)d_in[10], rcW1b, 6 * 512 * 512);
    cvt((const float*)d_in[12], rcW2b, 6 * 512 * 512);
    cvt((const float*)d_in[14], rcW3b, 6 * 256 * 512);
    cvt((const float*)d_in[4],  rsW1b, 12 * 256 * 256);
    cvt((const float*)d_in[6],  rsW2b, 12 * 256 * 256);
    cvt((const float*)d_in[8],  rsW3b, 12 * 256 * 256);

    // ---- all embed_ops upfront (depend only on feats) ----
    embed_all<<<dim3(NLVL * (NN / 16)), dim3(256), 0, stream>>>(feats, We, be, ebuf, out);

    // ---- flat descriptor helpers ----
    struct HD {
        const unsigned short *A, *B; const float* bias; const unsigned short* res;
        unsigned short* ob; float* of; int lda, ldb, ldr, ldo, resW, K, nblk;
    };
    auto D = [&](const unsigned short* A, int lda, const unsigned short* B, int ldb,
                 int N, int K, const float* bias,
                 const unsigned short* res, int ldr, int resW,
                 unsigned short* ob, int ldo, float* of) -> HD {
        HD h; h.A = A; h.B = B; h.bias = bias; h.res = res; h.ob = ob; h.of = of;
        h.lda = lda; h.ldb = ldb; h.ldr = ldr; h.ldo = ldo; h.resW = resW;
        h.K = K; h.nblk = 256 * (N / 128);
        return h;
    };
    auto GB = [&](const HD& a, const HD& b) {
        gemm_pair<<<dim3(a.nblk + b.nblk), dim3(256), 0, stream>>>(
            a.A, a.B, a.bias, a.res, a.ob, a.of, a.lda, a.ldb, a.ldr, a.ldo, a.resW, a.K,
            b.A, b.B, b.bias, b.res, b.ob, b.of, b.lda, b.ldb, b.ldr, b.ldo, b.resW, b.K,
            a.nblk);
    };
    auto G1 = [&](const HD& a) {
        gemm_pair<<<dim3(a.nblk), dim3(256), 0, stream>>>(
            a.A, a.B, a.bias, a.res, a.ob, a.of, a.lda, a.ldb, a.ldr, a.ldo, a.resW, a.K,
            a.A, a.B, a.bias, a.res, a.ob, a.of, a.lda, a.ldb, a.ldr, a.ldo, a.resW, a.K,
            a.nblk);
    };

    auto sw = [&](unsigned short* base, int i) { return base + (size_t)i * 256 * 256; };
    // comb chain descriptors for level l (writes e'(l) into dst[:, :256], ld 512)
    auto combD = [&](int l, int step, unsigned short* dst) -> HD {
        const int d = (l - 1 < 2) ? (l - 1) : 2;
        const unsigned short* el = ebuf + (size_t)l * NN * 256;
        const unsigned short* cw1 = rcW1b + (size_t)(3 + d) * 512 * 512;
        const unsigned short* cw2 = rcW2b + (size_t)(3 + d) * 512 * 512;
        const unsigned short* cw3 = rcW3b + (size_t)(3 + d) * 256 * 512;
        switch (step) {
        case 0: return D(el, 256, cw1, 512, 512, 256, rc_b1 + (3 + d) * 512, nullptr, 0, 0, p1, 512, nullptr);
        case 1: return D(p1, 512, cw2, 512, 512, 512, rc_b2 + (3 + d) * 512, el, 256, 256, p2, 512, nullptr);
        case 2: return D(p2, 512, cw3, 512, 256, 512, rc_b3 + (3 + d) * 256, nullptr, 0, 0, Tb, 256, nullptr);
        case 3: return D(Tb, 256, sw(rsW1b, 9 + d), 256, 256, 256, rs_b1 + (9 + d) * 256, nullptr, 0, 0, c1, 256, nullptr);
        case 4: return D(c1, 256, sw(rsW2b, 9 + d), 256, 256, 256, rs_b2 + (9 + d) * 256, Tb, 256, 256, c2, 256, nullptr);
        default:return D(c2, 256, sw(rsW3b, 9 + d), 256, 256, 256, rs_b3 + (9 + d) * 256, nullptr, 0, 0, dst, 512, nullptr);
        }
    };
    auto msgD = [&](int l, int step, unsigned short* dst) -> HD {
        const int d = (l - 1 < 2) ? (l - 1) : 2;
        switch (step) {
        case 0: return D(msgb, 256, sw(rsW1b, 2 * d), 256, 256, 256, rs_b1 + (2 * d) * 256, nullptr, 0, 0, t1, 256, nullptr);
        case 1: return D(t1, 256, sw(rsW2b, 2 * d), 256, 256, 256, rs_b2 + (2 * d) * 256, msgb, 256, 256, t2, 256, nullptr);
        case 2: return D(t2, 256, sw(rsW3b, 2 * d), 256, 256, 256, rs_b3 + (2 * d) * 256, nullptr, 0, 0, t3, 256, nullptr);
        case 3: return D(t3, 256, sw(rsW1b, 2 * d + 1), 256, 256, 256, rs_b1 + (2 * d + 1) * 256, nullptr, 0, 0, t1, 256, nullptr);
        case 4: return D(t1, 256, sw(rsW2b, 2 * d + 1), 256, 256, 256, rs_b2 + (2 * d + 1) * 256, t3, 256, 256, t2, 256, nullptr);
        default:return D(t2, 256, sw(rsW3b, 2 * d + 1), 256, 256, 256, rs_b3 + (2 * d + 1) * 256, nullptr, 0, 0, dst, 512, nullptr);
        }
    };

    const unsigned short* ep = ebuf;   // embeds[l-1]; level 0 final = embed_op(0)
    unsigned short* ebc = ebfA;
    unsigned short* ebn = ebfB;

    // comb(1) upfront (solo): e'(1) -> p0A[:, :256]   (level 1 parity = A)
    for (int st = 0; st < 6; ++st) G1(combD(1, st, p0A));

    for (int l = 1; l < NLVL; ++l) {
        const int d = (l - 1 < 2) ? (l - 1) : 2;
        unsigned short* p0cur = (l & 1) ? p0A : p0B;    // [e'(l), r(l)]
        unsigned short* p0nxt = (l & 1) ? p0B : p0A;    // e'(l+1) target
        const int* idx_l = pred_idx + (size_t)(l - 1) * NN * KFAN;

        // msg gather from embeds[l-1]
        gather_kernel<<<dim3(NN), dim3(256), 0, stream>>>(ep, idx_l, msgb);

        // msg(l) steps paired with comb(l+1) steps
        for (int st = 0; st < 6; ++st) {
            HD m = msgD(l, st, p0cur + 256);            // M6 -> r(l)
            if (l + 1 < NLVL) GB(m, combD(l + 1, st, p0nxt));
            else              G1(m);
        }

        // node chain (solo): p1/p2/Tb/c1/c2 free again (comb(l+1) finished)
        const unsigned short* nw1 = rcW1b + (size_t)d * 512 * 512;
        const unsigned short* nw2 = rcW2b + (size_t)d * 512 * 512;
        const unsigned short* nw3 = rcW3b + (size_t)d * 256 * 512;
        G1(D(p0cur, 512, nw1, 512, 512, 512, rc_b1 + d * 512, nullptr, 0, 0, p1, 512, nullptr));
        G1(D(p1, 512, nw2, 512, 512, 512, rc_b2 + d * 512, p0cur, 512, 512, p2, 512, nullptr));
        G1(D(p2, 512, nw3, 512, 256, 512, rc_b3 + d * 256, nullptr, 0, 0, Tb, 256, nullptr));
        G1(D(Tb, 256, sw(rsW1b, 6 + d), 256, 256, 256, rs_b1 + (6 + d) * 256, nullptr, 0, 0, c1, 256, nullptr));
        G1(D(c1, 256, sw(rsW2b, 6 + d), 256, 256, 256, rs_b2 + (6 + d) * 256, Tb, 256, 256, c2, 256, nullptr));
        G1(D(c2, 256, sw(rsW3b, 6 + d), 256, 256, 256, rs_b3 + (6 + d) * 256, nullptr, 0, 0, ebc, 256,
             out + (size_t)l * NN * HDIM));

        ep = ebc;
        unsigned short* t = ebc; ebc = ebn; ebn = t;
    }
}